// Round 4
// baseline (59.179 us; speedup 1.0000x reference)
//
#include <hip/hip_runtime.h>

#define NB  16
#define NTQ 64
#define NTV 256
#define ND  512
#define NU  512

typedef _Float16 half8_t __attribute__((ext_vector_type(8)));
typedef _Float16 half4_t __attribute__((ext_vector_type(4)));
typedef float floatx4 __attribute__((ext_vector_type(4)));

__device__ __forceinline__ float wred_sum(float x) {
#pragma unroll
    for (int m = 1; m < 64; m <<= 1) x += __shfl_xor(x, m, 64);
    return x;
}
__device__ __forceinline__ float wred_max(float x) {
#pragma unroll
    for (int m = 1; m < 64; m <<= 1) x = fmaxf(x, __shfl_xor(x, m, 64));
    return x;
}

// ---------------- K1: prep (transpose W1/W2 -> f16, convert query/values -> f16, CVb = Vb + sum(Vw))
__global__ __launch_bounds__(256) void prep_kernel(
        const float* __restrict__ W1, const float* __restrict__ W2,
        const float* __restrict__ query, const float* __restrict__ values,
        const float* __restrict__ Vw, const float* __restrict__ Vb,
        _Float16* __restrict__ W1T, _Float16* __restrict__ W2T,
        _Float16* __restrict__ qh, _Float16* __restrict__ vh,
        float* __restrict__ CVb) {
    const int blk = blockIdx.x;
    const int t = threadIdx.x;
    __shared__ float tb[32][33];
    if (blk < 512) {
        const float* W = (blk < 256) ? W1 : W2;
        _Float16* WT = (blk < 256) ? W1T : W2T;
        const int tile = blk & 255;
        const int tr = tile >> 4, tc = tile & 15;
        const int c = t & 31, r8 = t >> 5;
#pragma unroll
        for (int i = 0; i < 4; ++i) {
            int r = r8 + 8 * i;
            tb[r][c] = W[(tr * 32 + r) * 512 + tc * 32 + c];
        }
        __syncthreads();
#pragma unroll
        for (int i = 0; i < 4; ++i) {
            int r = r8 + 8 * i;
            WT[(tc * 32 + r) * 512 + tr * 32 + c] = (_Float16)tb[c][r];
        }
    } else if (blk < 1792) {
        const bool isQ = blk < 768;
        const float* src = isQ ? query : values;
        _Float16* dst = isQ ? qh : vh;
        const int base = (isQ ? (blk - 512) : (blk - 768)) * 2048 + t * 8;
        float4 f0 = *(const float4*)(src + base);
        float4 f1 = *(const float4*)(src + base + 4);
        half8_t h;
        h[0] = (_Float16)f0.x; h[1] = (_Float16)f0.y;
        h[2] = (_Float16)f0.z; h[3] = (_Float16)f0.w;
        h[4] = (_Float16)f1.x; h[5] = (_Float16)f1.y;
        h[6] = (_Float16)f1.z; h[7] = (_Float16)f1.w;
        *(half8_t*)(dst + base) = h;
    } else {
        float s = Vw[t] + Vw[t + 256];
        s = wred_sum(s);
        const int l = t & 63, w = t >> 6;
        __shared__ float ws4[4];
        if (l == 0) ws4[w] = s;
        __syncthreads();
        if (t == 0) CVb[0] = ws4[0] + ws4[1] + ws4[2] + ws4[3] + Vb[0];
    }
}

// ---------------- K2: fused projections, f16 MFMA; epilogue writes EXP2 of scaled proj:
// bid < 32 : Eq[m=(b,q)][u] = exp2(KC*(query@W1 + b1))              f32
// bid >= 32: Evh[b][u][v]   = f16(min(exp2(KC*(W2T@valuesT + b2)), 60000))
// so e^{2(q_proj+v_proj)} = Eq*Ev   (KC = 2*log2 e); f16 sat -> tanh limit, graceful
__global__ __launch_bounds__(256) void proj_gemm_kernel(
        const _Float16* __restrict__ qh, const _Float16* __restrict__ vh,
        const _Float16* __restrict__ W1T, const _Float16* __restrict__ W2T,
        const float* __restrict__ b1, const float* __restrict__ b2,
        float* __restrict__ Eq, _Float16* __restrict__ Evh) {
    __shared__ __align__(16) _Float16 As[128 * 40];
    __shared__ __align__(16) _Float16 Bs[128 * 40];
    const float KC = 2.8853900817779268f;  // 2*log2(e)
    const int bid = blockIdx.x;
    const int t = threadIdx.x;
    const int l = t & 63, w = t >> 6;

    const _Float16* Ag; const _Float16* Bg;
    const float* bias;
    int ldc, tm, tn; bool isV;
    float* Cq = nullptr; _Float16* Cv = nullptr;
    if (bid < 32) {
        tm = (bid >> 2) * 128; tn = (bid & 3) * 128;
        Ag = qh; Bg = W1T; bias = b1; Cq = Eq; ldc = NU; isV = false;
    } else {
        const int v = bid - 32;
        const int bb = v >> 3, r = v & 7;
        tm = (r >> 1) * 128; tn = (r & 1) * 128;
        Ag = W2T; Bg = vh + bb * (NTV * ND); bias = b2;
        Cv = Evh + bb * (NU * NTV); ldc = NTV; isV = true;
    }

    floatx4 acc[4][4] = {};

    const int srow = t >> 1, spart = (t & 1) * 16;
    const int wm = (w >> 1) * 64, wn = (w & 1) * 64;
    const int lr = l & 15, lk = l >> 4;

    for (int kk = 0; kk < 512; kk += 32) {
        __syncthreads();
        half8_t a0 = *(const half8_t*)(Ag + (tm + srow) * 512 + kk + spart);
        half8_t a1 = *(const half8_t*)(Ag + (tm + srow) * 512 + kk + spart + 8);
        half8_t bb0 = *(const half8_t*)(Bg + (tn + srow) * 512 + kk + spart);
        half8_t bb1 = *(const half8_t*)(Bg + (tn + srow) * 512 + kk + spart + 8);
        *(half8_t*)(As + srow * 40 + spart) = a0;
        *(half8_t*)(As + srow * 40 + spart + 8) = a1;
        *(half8_t*)(Bs + srow * 40 + spart) = bb0;
        *(half8_t*)(Bs + srow * 40 + spart + 8) = bb1;
        __syncthreads();
        half8_t af[4], bf[4];
#pragma unroll
        for (int i = 0; i < 4; ++i)
            af[i] = *(const half8_t*)(As + (wm + 16 * i + lr) * 40 + lk * 8);
#pragma unroll
        for (int j = 0; j < 4; ++j)
            bf[j] = *(const half8_t*)(Bs + (wn + 16 * j + lr) * 40 + lk * 8);
#pragma unroll
        for (int i = 0; i < 4; ++i)
#pragma unroll
            for (int j = 0; j < 4; ++j)
                acc[i][j] = __builtin_amdgcn_mfma_f32_16x16x32_f16(af[i], bf[j], acc[i][j], 0, 0, 0);
    }

    // C/D layout: col = lane&15, row = (lane>>4)*4 + reg
#pragma unroll
    for (int i = 0; i < 4; ++i) {
#pragma unroll
        for (int j = 0; j < 4; ++j) {
            const int gr0 = tm + wm + 16 * i + lk * 4;
            const int gc = tn + wn + 16 * j + lr;
#pragma unroll
            for (int r = 0; r < 4; ++r) {
                const int gr = gr0 + r;
                const float bv = isV ? bias[gr] : bias[gc];
                const float e = __builtin_amdgcn_exp2f(KC * (acc[i][j][r] + bv));
                if (isV) Cv[gr * ldc + gc] = (_Float16)fminf(e, 60000.f);
                else     Cq[gr * ldc + gc] = e;
            }
        }
    }
}

// ---------------- K3: fused score + mask + softmax + context, 4 q per block (grid 256)
// score = CVb - 2 * sum_u Vw[u] / (1 + Eq[u]*Ev[u][v])   (1 trans/element)
// Per-XCD L2 traffic: 2 batches x 16 blocks x (256KB Evh + 256KB vh) = 16 MB (was 64).
__global__ __launch_bounds__(1024) void score_kernel(
        const float* __restrict__ Eq, const _Float16* __restrict__ Evh,
        const _Float16* __restrict__ vh, const int* __restrict__ enc_mask,
        const float* __restrict__ CVbp, const float* __restrict__ Vw,
        float* __restrict__ out) {
    const int bid = blockIdx.x;
    const int b = bid & 15, qg = bid >> 4;   // blocks of batch b -> XCD b%8
    const int q0 = qg * 4;
    const int t = threadIdx.x;

    __shared__ float pacc[4][16][256];   // 64 KB
    __shared__ float attL[4][256];       //  4 KB
    __shared__ float ctxp[4][8][520];    // 65 KB (pad 520 vs power-of-2 stride)
    __shared__ float rs[4][4], ss[4][4];

    const _Float16* evb = Evh + b * (NU * NTV);
    const float* qb = Eq + (b * NTQ + q0) * NU;

    // ---- score phase: thread = (ug 0..15, vq 0..63); u-range 32, 4 v, 4 q
    {
        const int ug = t >> 6;           // wave-uniform
        const int vq = t & 63;
        floatx4 a0 = {0.f,0.f,0.f,0.f}, a1 = {0.f,0.f,0.f,0.f};
        floatx4 a2 = {0.f,0.f,0.f,0.f}, a3 = {0.f,0.f,0.f,0.f};
        const int ub = ug * 32;
#pragma unroll 4
        for (int u = ub; u < ub + 32; ++u) {
            const float vw = Vw[u];
            const float eq0 = qb[u];
            const float eq1 = qb[u + 512];
            const float eq2 = qb[u + 1024];
            const float eq3 = qb[u + 1536];
            const half4_t evh4 = *(const half4_t*)(evb + u * NTV + vq * 4);
            const floatx4 ev = { (float)evh4[0], (float)evh4[1], (float)evh4[2], (float)evh4[3] };
#pragma unroll
            for (int j = 0; j < 4; ++j) {
                a0[j] = fmaf(vw, __builtin_amdgcn_rcpf(fmaf(eq0, ev[j], 1.f)), a0[j]);
                a1[j] = fmaf(vw, __builtin_amdgcn_rcpf(fmaf(eq1, ev[j], 1.f)), a1[j]);
                a2[j] = fmaf(vw, __builtin_amdgcn_rcpf(fmaf(eq2, ev[j], 1.f)), a2[j]);
                a3[j] = fmaf(vw, __builtin_amdgcn_rcpf(fmaf(eq3, ev[j], 1.f)), a3[j]);
            }
        }
        *(floatx4*)&pacc[0][ug][vq * 4] = a0;
        *(floatx4*)&pacc[1][ug][vq * 4] = a1;
        *(floatx4*)&pacc[2][ug][vq * 4] = a2;
        *(floatx4*)&pacc[3][ug][vq * 4] = a3;
    }
    __syncthreads();

    // ---- softmax: q = t>>8 (0..3), v = t&255; 4 waves per q
    const int q = t >> 8, v = t & 255;
    const int l = t & 63, w4 = (t >> 6) & 3;
    float sc, ee;
    {
        float s = 0.f;
#pragma unroll
        for (int g = 0; g < 16; ++g) s += pacc[q][g][v];
        sc = CVbp[0] - 2.f * s;
        sc -= enc_mask[b * NTV + v] ? 0.f : 1e9f;
        float m = wred_max(sc);
        if (l == 0) rs[q][w4] = m;
    }
    __syncthreads();
    {
        const float m = fmaxf(fmaxf(rs[q][0], rs[q][1]), fmaxf(rs[q][2], rs[q][3]));
        const float LOG2E = 1.4426950408889634f;
        ee = __builtin_amdgcn_exp2f((sc - m) * LOG2E);
        float t0 = wred_sum(ee);
        if (l == 0) ss[q][w4] = t0;
    }
    __syncthreads();
    {
        const float S = (ss[q][0] + ss[q][1]) + (ss[q][2] + ss[q][3]);
        const float a = ee * __builtin_amdgcn_rcpf(S);
        attL[q][v] = a;
        float* out_attn = out + NB * NTQ * ND;
        out_attn[(b * NTQ + q0 + q) * NTV + v] = a;
    }
    __syncthreads();

    // ---- context: thread = (vg 0..7, dq 0..127), all 4 q; f16 values (vh), dwordx2 loads
    {
        const int vg = t >> 7;
        const int dq = t & 127;
        const _Float16* vsrc = vh + (b * NTV + vg * 32) * ND + dq * 4;
        floatx4 c0 = {0.f,0.f,0.f,0.f}, c1 = {0.f,0.f,0.f,0.f};
        floatx4 c2 = {0.f,0.f,0.f,0.f}, c3 = {0.f,0.f,0.f,0.f};
        const float* aL0 = &attL[0][vg * 32];
        const float* aL1 = &attL[1][vg * 32];
        const float* aL2 = &attL[2][vg * 32];
        const float* aL3 = &attL[3][vg * 32];
#pragma unroll 4
        for (int vi = 0; vi < 32; ++vi) {
            const half4_t vvh = *(const half4_t*)(vsrc + vi * ND);
            const floatx4 vv = { (float)vvh[0], (float)vvh[1], (float)vvh[2], (float)vvh[3] };
            const float w0 = aL0[vi], w1 = aL1[vi], w2 = aL2[vi], w3 = aL3[vi];
#pragma unroll
            for (int j = 0; j < 4; ++j) {
                c0[j] = fmaf(w0, vv[j], c0[j]);
                c1[j] = fmaf(w1, vv[j], c1[j]);
                c2[j] = fmaf(w2, vv[j], c2[j]);
                c3[j] = fmaf(w3, vv[j], c3[j]);
            }
        }
        *(floatx4*)&ctxp[0][vg][dq * 4] = c0;
        *(floatx4*)&ctxp[1][vg][dq * 4] = c1;
        *(floatx4*)&ctxp[2][vg][dq * 4] = c2;
        *(floatx4*)&ctxp[3][vg][dq * 4] = c3;
    }
    __syncthreads();
#pragma unroll
    for (int k = 0; k < 2; ++k) {
        const int idx = t + k * 1024;
        const int cq = idx >> 9, d = idx & 511;
        float s = 0.f;
#pragma unroll
        for (int g = 0; g < 8; ++g) s += ctxp[cq][g][d];
        out[(b * NTQ + q0 + cq) * ND + d] = s;
    }
}

extern "C" void kernel_launch(void* const* d_in, const int* in_sizes, int n_in,
                              void* d_out, int out_size, void* d_ws, size_t ws_size,
                              hipStream_t stream) {
    const float* query  = (const float*)d_in[0];
    const float* values = (const float*)d_in[1];
    const int*   emask  = (const int*)d_in[2];
    const float* W1     = (const float*)d_in[3];
    const float* b1     = (const float*)d_in[4];
    const float* W2     = (const float*)d_in[5];
    const float* b2     = (const float*)d_in[6];
    const float* Vw     = (const float*)d_in[7];
    const float* Vb     = (const float*)d_in[8];
    float* out = (float*)d_out;

    char* ws = (char*)d_ws;
    _Float16* W1T = (_Float16*)(ws + 0);         //  512 KB  [U][D] f16
    _Float16* W2T = (_Float16*)(ws + 524288);    //  512 KB  [U][D] f16
    _Float16* qh  = (_Float16*)(ws + 1048576);   //    1 MB  [B*TQ][D] f16
    _Float16* vh  = (_Float16*)(ws + 2097152);   //    4 MB  [B*TV][D] f16
    float* Eq     = (float*)(ws + 6291456);      //    2 MB  [B*TQ][U] f32 exp2-scaled
    _Float16* Evh = (_Float16*)(ws + 8388608);   //    4 MB  [B][U][TV] f16 exp2-scaled
    float* CVb    = (float*)(ws + 16777216);     //    4 B

    prep_kernel<<<dim3(1793), dim3(256), 0, stream>>>(W1, W2, query, values, Vw, Vb,
                                                      W1T, W2T, qh, vh, CVb);
    proj_gemm_kernel<<<dim3(160), dim3(256), 0, stream>>>(qh, vh, W1T, W2T, b1, b2, Eq, Evh);
    score_kernel<<<dim3(256), dim3(1024), 0, stream>>>(Eq, Evh, vh, emask, CVb, Vw, out);
}